// Round 9
// baseline (190.393 us; speedup 1.0000x reference)
//
#include <hip/hip_runtime.h>
#include <hip/hip_fp16.h>

#define FEAT1 64
#define FEAT2 16
#define NCHUNK_R 800   // radix chunks
#define NB 1024        // coarse buckets
#define SHB 6          // node id -> bucket shift (64 nodes/bucket)

typedef _Float16 f16x8 __attribute__((ext_vector_type(8)));
typedef _Float16 f16x4 __attribute__((ext_vector_type(4)));
typedef float f32x4 __attribute__((ext_vector_type(4)));

// K1: per-chunk 1024-bin coarse histograms of src>>6 and dst>>6
__global__ __launch_bounds__(256) void coarse_hist(const int* __restrict__ src,
                                                   const int* __restrict__ dst,
                                                   int* __restrict__ partS, int* __restrict__ partD,
                                                   int E, int chunkE) {
    __shared__ int hS[NB], hD[NB];
    int tid = threadIdx.x, chunk = blockIdx.x;
    for (int i = tid; i < NB; i += 256) { hS[i] = 0; hD[i] = 0; }
    __syncthreads();
    int e0 = chunk * chunkE, e1 = min(E, e0 + chunkE);
    for (int e = e0 + tid; e < e1; e += 256) {
        atomicAdd(&hS[src[e] >> SHB], 1);
        atomicAdd(&hD[dst[e] >> SHB], 1);
    }
    __syncthreads();
    for (int i = tid; i < NB; i += 256) {
        partS[chunk * NB + i] = hS[i];
        partD[chunk * NB + i] = hD[i];
    }
}

// K2: per-bin exclusive scan over chunks; grid 2*NB
__global__ __launch_bounds__(256) void scan_chunks(int* partS, int* partD,
                                                   int* totS, int* totD, int nchunk) {
    __shared__ int sums[256];
    int tid = threadIdx.x;
    int bin = blockIdx.x & (NB - 1);
    int* part = (blockIdx.x >> 10) ? partD : partS;
    int* tot  = (blockIdx.x >> 10) ? totD : totS;
    int v[4];
    int base = tid * 4, local = 0;
#pragma unroll
    for (int j = 0; j < 4; j++) {
        int c = base + j;
        v[j] = (c < nchunk) ? part[c * NB + bin] : 0;
        local += v[j];
    }
    sums[tid] = local;
    __syncthreads();
    for (int off = 1; off < 256; off <<= 1) {
        int t = (tid >= off) ? sums[tid - off] : 0;
        __syncthreads();
        sums[tid] += t;
        __syncthreads();
    }
    int run = sums[tid] - local;
#pragma unroll
    for (int j = 0; j < 4; j++) {
        int c = base + j;
        if (c < nchunk) part[c * NB + bin] = run;
        run += v[j];
    }
    if (tid == 255) tot[bin] = run;
}

// K3: exclusive scan of NB bucket totals (both sides), one block, 4 bins/thread
__global__ __launch_bounds__(256) void scan_bins(const int* __restrict__ totS,
                                                 const int* __restrict__ totD,
                                                 int* baseS, int* baseD) {
    __shared__ int s[256];
    int tid = threadIdx.x, base = tid * 4;
    int v[4], local = 0;
#pragma unroll
    for (int j = 0; j < 4; j++) { v[j] = totS[base + j]; local += v[j]; }
    s[tid] = local;
    __syncthreads();
    for (int off = 1; off < 256; off <<= 1) {
        int t = (tid >= off) ? s[tid - off] : 0;
        __syncthreads();
        s[tid] += t;
        __syncthreads();
    }
    int run = s[tid] - local;
#pragma unroll
    for (int j = 0; j < 4; j++) { baseS[base + j] = run; run += v[j]; }
    __syncthreads();
    local = 0;
#pragma unroll
    for (int j = 0; j < 4; j++) { v[j] = totD[base + j]; local += v[j]; }
    s[tid] = local;
    __syncthreads();
    for (int off = 1; off < 256; off <<= 1) {
        int t = (tid >= off) ? s[tid - off] : 0;
        __syncthreads();
        s[tid] += t;
        __syncthreads();
    }
    run = s[tid] - local;
#pragma unroll
    for (int j = 0; j < 4; j++) { baseD[base + j] = run; run += v[j]; }
}

// K4: coarse partition with LDS cursors
__global__ __launch_bounds__(256) void partition_coarse(const int* __restrict__ src,
                                                        const int* __restrict__ dst,
                                                        const int* __restrict__ partS,
                                                        const int* __restrict__ partD,
                                                        const int* __restrict__ baseS,
                                                        const int* __restrict__ baseD,
                                                        unsigned int* __restrict__ packD,
                                                        unsigned char* __restrict__ srcLow,
                                                        int E, int chunkE) {
    __shared__ int curS[NB], curD[NB];
    int tid = threadIdx.x, chunk = blockIdx.x;
    for (int i = tid; i < NB; i += 256) {
        curS[i] = baseS[i] + partS[chunk * NB + i];
        curD[i] = baseD[i] + partD[chunk * NB + i];
    }
    __syncthreads();
    int e0 = chunk * chunkE, e1 = min(E, e0 + chunkE);
    for (int e = e0 + tid; e < e1; e += 256) {
        int s = src[e], d = dst[e];
        int pD = atomicAdd(&curD[d >> SHB], 1);
        packD[pD] = ((unsigned)(d & 63) << 16) | (unsigned)s;
        int pS = atomicAdd(&curS[s >> SHB], 1);
        srcLow[pS] = (unsigned char)(s & 63);
    }
}

// K5: fine sort within each dst bucket (64 nodes); emits offs/cnt/norm_dst + sorted_src
__global__ __launch_bounds__(256) void fine_dst(const unsigned int* __restrict__ packD,
                                                const int* __restrict__ baseD,
                                                const int* __restrict__ totD,
                                                int* __restrict__ sorted_src,
                                                int* __restrict__ offs, int* __restrict__ cnt,
                                                float* __restrict__ norm_dst, int N) {
    __shared__ int hist[64], pfx[64], cur[64];
    int tid = threadIdx.x, b = blockIdx.x;
    int lo = baseD[b], n = totD[b];
    if (tid < 64) hist[tid] = 0;
    __syncthreads();
    for (int i = lo + tid; i < lo + n; i += 256) atomicAdd(&hist[packD[i] >> 16], 1);
    __syncthreads();
    int v = 0;
    if (tid < 64) { v = hist[tid]; pfx[tid] = v; }
    __syncthreads();
    for (int off = 1; off < 64; off <<= 1) {
        int t = 0;
        if (tid < 64 && tid >= off) t = pfx[tid - off];
        __syncthreads();
        if (tid < 64) pfx[tid] += t;
        __syncthreads();
    }
    if (tid < 64) {
        int my = pfx[tid] - v;
        cur[tid] = lo + my;
        int node = b * 64 + tid;
        if (node < N) {
            offs[node] = lo + my;
            cnt[node] = v;
            norm_dst[node] = rsqrtf(fmaxf((float)v, 1.0f));
        }
    }
    __syncthreads();
    for (int i = lo + tid; i < lo + n; i += 256) {
        unsigned p = packD[i];
        int pos = atomicAdd(&cur[p >> 16], 1);
        sorted_src[pos] = (int)(p & 0xFFFFu);
    }
}

// K6: fine src histogram per bucket -> norm_src
__global__ __launch_bounds__(256) void fine_src(const unsigned char* __restrict__ srcLow,
                                                const int* __restrict__ baseS,
                                                const int* __restrict__ totS,
                                                float* __restrict__ norm_src, int N) {
    __shared__ int hist[64];
    int tid = threadIdx.x, b = blockIdx.x;
    int lo = baseS[b], n = totS[b];
    if (tid < 64) hist[tid] = 0;
    __syncthreads();
    for (int i = lo + tid; i < lo + n; i += 256) atomicAdd(&hist[srcLow[i]], 1);
    __syncthreads();
    if (tid < 64) {
        int node = b * 64 + tid;
        if (node < N) norm_src[node] = rsqrtf(fmaxf((float)hist[tid], 1.0f));
    }
}

// ---------------- MFMA GEMM layer 1 (R6/R8 proven) ----------------

__global__ __launch_bounds__(256) void gemm1_kernel(const float* __restrict__ X,
                                                    const float* __restrict__ W1,
                                                    const float* __restrict__ norm_src,
                                                    __half* __restrict__ h1, int N) {
    __shared__ _Float16 sWt[64 * 72];
    __shared__ float snorm[128];
    __shared__ _Float16 sTile[4][16 * 72];
    int tid = threadIdx.x;
    int row_blk = blockIdx.x * 128;
    for (int i = tid; i < 4096; i += 256) {
        int k = i >> 6, n = i & 63;
        sWt[n * 72 + k] = (_Float16)W1[i];
    }
    if (tid < 128) {
        int r = row_blk + tid;
        snorm[tid] = (r < N) ? norm_src[r] : 0.f;
    }
    __syncthreads();
    int wave = tid >> 6, lane = tid & 63;
    int m = lane & 15, quad = lane >> 4;
    f16x8 bfrag[4][2];
#pragma unroll
    for (int nt = 0; nt < 4; nt++)
#pragma unroll
        for (int kit = 0; kit < 2; kit++)
            bfrag[nt][kit] = *(const f16x8*)&sWt[(nt * 16 + m) * 72 + kit * 32 + quad * 8];
    _Float16* tile = sTile[wave];
#pragma unroll
    for (int t = 0; t < 2; t++) {
        int row0 = row_blk + wave * 32 + t * 16;
        int row = row0 + m;
        bool inb = row < N;
        f32x4 acc[4] = {{0.f,0.f,0.f,0.f},{0.f,0.f,0.f,0.f},{0.f,0.f,0.f,0.f},{0.f,0.f,0.f,0.f}};
#pragma unroll
        for (int kit = 0; kit < 2; kit++) {
            f16x8 afrag;
            if (inb) {
                const float4* xp = (const float4*)(X + (size_t)row * 64 + kit * 32 + quad * 8);
                float4 x0 = xp[0], x1 = xp[1];
                afrag[0] = (_Float16)x0.x; afrag[1] = (_Float16)x0.y;
                afrag[2] = (_Float16)x0.z; afrag[3] = (_Float16)x0.w;
                afrag[4] = (_Float16)x1.x; afrag[5] = (_Float16)x1.y;
                afrag[6] = (_Float16)x1.z; afrag[7] = (_Float16)x1.w;
            } else {
#pragma unroll
                for (int j = 0; j < 8; j++) afrag[j] = (_Float16)0.f;
            }
#pragma unroll
            for (int nt = 0; nt < 4; nt++)
                acc[nt] = __builtin_amdgcn_mfma_f32_16x16x32_f16(afrag, bfrag[nt][kit], acc[nt], 0, 0, 0);
        }
#pragma unroll
        for (int reg = 0; reg < 4; reg++) {
            int r = quad * 4 + reg;
            float nrm = snorm[wave * 32 + t * 16 + r];
#pragma unroll
            for (int nt = 0; nt < 4; nt++)
                tile[r * 72 + nt * 16 + m] = (_Float16)(acc[nt][reg] * nrm);
        }
        __syncthreads();
        int rr = lane >> 2, g = lane & 3;
        f16x8 p0 = *(const f16x8*)&tile[rr * 72 + g * 16];
        f16x8 p1 = *(const f16x8*)&tile[rr * 72 + g * 16 + 8];
        int orow = row0 + rr;
        if (orow < N) {
            *(f16x8*)((_Float16*)h1 + (size_t)orow * 64 + g * 16) = p0;
            *(f16x8*)((_Float16*)h1 + (size_t)orow * 64 + g * 16 + 8) = p1;
        }
        __syncthreads();
    }
}

// ---------------- fused agg1 + relu + W2 matvec -> h2 ----------------
// wave per row (grid-stride); gather: fg(0..7)=16B feat group, e_off(0..7)=edge slot.
// After butterfly every lane holds full row; per-lane W2/b1 registers do the
// 64x16 matvec (2 cols/lane), shfl-reduce over fg, store h2.
__global__ __launch_bounds__(256) void agg1_fused(const __half* __restrict__ h1,
                                                  const int* __restrict__ sorted_src,
                                                  const int* __restrict__ offs,
                                                  const int* __restrict__ cnt,
                                                  const float* __restrict__ norm_dst,
                                                  const float* __restrict__ norm_src,
                                                  const float* __restrict__ b1,
                                                  const float* __restrict__ W2,
                                                  __half* __restrict__ h2, int N, int nwaves) {
    int tid = threadIdx.x;
    int wave = tid >> 6, lane = tid & 63;
    int e_off = lane >> 3;   // 0..7
    int fg = lane & 7;       // feats 8fg..8fg+7
    float w2r[8][2], b1r[8];
#pragma unroll
    for (int k = 0; k < 8; k++) {
        float2 t = *(const float2*)(W2 + (size_t)(fg * 8 + k) * 16 + 2 * e_off);
        w2r[k][0] = t.x; w2r[k][1] = t.y;
        b1r[k] = b1[fg * 8 + k];
    }
    const _Float16* h1p = (const _Float16*)h1;
    for (int row = blockIdx.x * 4 + wave; row < N; row += nwaves) {
        int start = offs[row], c = cnt[row];
        float nd = norm_dst[row];
        float acc[8] = {0.f, 0.f, 0.f, 0.f, 0.f, 0.f, 0.f, 0.f};
        for (int j = 0; j < c; j += 8) {
            int je = j + e_off;
            if (je < c) {
                int s = sorted_src[start + je];
                f16x8 v = *(const f16x8*)(h1p + (size_t)s * 64 + fg * 8);
#pragma unroll
                for (int k = 0; k < 8; k++) acc[k] += (float)v[k];
            }
        }
#pragma unroll
        for (int m = 8; m <= 32; m <<= 1)
#pragma unroll
            for (int k = 0; k < 8; k++) acc[k] += __shfl_xor(acc[k], m);
        float p0 = 0.f, p1 = 0.f;
#pragma unroll
        for (int k = 0; k < 8; k++) {
            float t = fmaxf(acc[k] * nd + b1r[k], 0.f);
            p0 += t * w2r[k][0];
            p1 += t * w2r[k][1];
        }
#pragma unroll
        for (int m = 1; m <= 4; m <<= 1) {
            p0 += __shfl_xor(p0, m);
            p1 += __shfl_xor(p1, m);
        }
        if (fg == 0) {
            float ns = norm_src[row];
            ((__half2*)((_Float16*)h2 + (size_t)row * 16))[e_off] =
                __floats2half2_rn(p0 * ns, p1 * ns);
        }
    }
}

// ---------------- layer-2 aggregation + epilogue (R8 proven) ----------------

__global__ __launch_bounds__(256) void agg2_kernel(const __half* __restrict__ h2,
                                                   const int* __restrict__ sorted_src,
                                                   const int* __restrict__ offs,
                                                   const int* __restrict__ cnt,
                                                   const float* __restrict__ norm_dst,
                                                   const float* __restrict__ b2,
                                                   float* __restrict__ out, int N) {
    int tid = threadIdx.x;
    int row = blockIdx.x * 4 + (tid >> 6);
    if (row >= N) return;
    int lane = tid & 63;
    int e_off = lane >> 2;   // 0..15
    int fg = lane & 3;       // feats 4fg..4fg+3
    int start = offs[row], c = cnt[row];
    float acc[4] = {0.f, 0.f, 0.f, 0.f};
    const _Float16* h2p = (const _Float16*)h2;
    for (int j = 0; j < c; j += 16) {
        int je = j + e_off;
        if (je < c) {
            int s = sorted_src[start + je];
            f16x4 v = *(const f16x4*)(h2p + (size_t)s * 16 + fg * 4);
#pragma unroll
            for (int k = 0; k < 4; k++) acc[k] += (float)v[k];
        }
    }
#pragma unroll
    for (int m = 4; m <= 32; m <<= 1)
#pragma unroll
        for (int k = 0; k < 4; k++) acc[k] += __shfl_xor(acc[k], m);
    if (e_off == 0) {
        float nd = norm_dst[row];
        float4 o;
        o.x = acc[0] * nd + b2[fg * 4 + 0];
        o.y = acc[1] * nd + b2[fg * 4 + 1];
        o.z = acc[2] * nd + b2[fg * 4 + 2];
        o.w = acc[3] * nd + b2[fg * 4 + 3];
        ((float4*)(out + (size_t)row * 16))[fg] = o;
    }
}

extern "C" void kernel_launch(void* const* d_in, const int* in_sizes, int n_in,
                              void* d_out, int out_size, void* d_ws, size_t ws_size,
                              hipStream_t stream) {
    const float* X  = (const float*)d_in[0];
    const int* src  = (const int*)d_in[1];
    const int* dst  = (const int*)d_in[2];
    const float* W1 = (const float*)d_in[3];
    const float* b1 = (const float*)d_in[4];
    const float* W2 = (const float*)d_in[5];
    const float* b2 = (const float*)d_in[6];
    float* out = (float*)d_out;

    const int N = in_sizes[0] / FEAT1;  // 50000
    const int E = in_sizes[1];          // 800000
    const int chunkE = (E + NCHUNK_R - 1) / NCHUNK_R;  // 1000

    char* w = (char*)d_ws;
    int* partS = (int*)w;        w += (size_t)NCHUNK_R * NB * 4;
    int* partD = (int*)w;        w += (size_t)NCHUNK_R * NB * 4;
    int* totS  = (int*)w;        w += NB * 4;
    int* totD  = (int*)w;        w += NB * 4;
    int* baseS = (int*)w;        w += NB * 4;
    int* baseD = (int*)w;        w += NB * 4;
    unsigned int* packD = (unsigned int*)w; w += (size_t)E * 4;
    int* sorted_src = (int*)w;   w += (size_t)E * 4;
    int* offs = (int*)w;         w += (size_t)N * 4;
    int* cnt  = (int*)w;         w += (size_t)N * 4;
    float* norm_src = (float*)w; w += (size_t)N * 4;
    float* norm_dst = (float*)w; w += (size_t)N * 4;
    __half* h1 = (__half*)w;     w += (size_t)N * 64 * 2;
    __half* h2 = (__half*)w;     w += (size_t)N * 16 * 2;
    unsigned char* srcLow = (unsigned char*)w; w += (size_t)E;

    coarse_hist<<<NCHUNK_R, 256, 0, stream>>>(src, dst, partS, partD, E, chunkE);
    scan_chunks<<<2 * NB, 256, 0, stream>>>(partS, partD, totS, totD, NCHUNK_R);
    scan_bins<<<1, 256, 0, stream>>>(totS, totD, baseS, baseD);
    partition_coarse<<<NCHUNK_R, 256, 0, stream>>>(src, dst, partS, partD, baseS, baseD,
                                                   packD, srcLow, E, chunkE);
    fine_dst<<<NB, 256, 0, stream>>>(packD, baseD, totD, sorted_src, offs, cnt, norm_dst, N);
    fine_src<<<NB, 256, 0, stream>>>(srcLow, baseS, totS, norm_src, N);
    gemm1_kernel<<<(N + 127) / 128, 256, 0, stream>>>(X, W1, norm_src, h1, N);
    const int nblk = 2048;
    agg1_fused<<<nblk, 256, 0, stream>>>(h1, sorted_src, offs, cnt, norm_dst, norm_src,
                                         b1, W2, h2, N, nblk * 4);
    agg2_kernel<<<(N + 3) / 4, 256, 0, stream>>>(h2, sorted_src, offs, cnt, norm_dst, b2, out, N);
}

// Round 10
// 181.419 us; speedup vs baseline: 1.0495x; 1.0495x over previous
//
#include <hip/hip_runtime.h>
#include <hip/hip_fp16.h>

#define FEAT1 64
#define FEAT2 16
#define NCHUNK_R 800   // radix chunks

typedef _Float16 f16x8 __attribute__((ext_vector_type(8)));
typedef _Float16 f16x4 __attribute__((ext_vector_type(4)));
typedef float f32x4 __attribute__((ext_vector_type(4)));

// ---------------- radix sort pipeline (R8-proven 256-bucket geometry) ----------------

__global__ __launch_bounds__(256) void coarse_hist(const int* __restrict__ src,
                                                   const int* __restrict__ dst,
                                                   int* __restrict__ partS, int* __restrict__ partD,
                                                   int E, int chunkE) {
    __shared__ int hS[256], hD[256];
    int tid = threadIdx.x, chunk = blockIdx.x;
    hS[tid] = 0; hD[tid] = 0;
    __syncthreads();
    int e0 = chunk * chunkE, e1 = min(E, e0 + chunkE);
    for (int e = e0 + tid; e < e1; e += 256) {
        atomicAdd(&hS[src[e] >> 8], 1);
        atomicAdd(&hD[dst[e] >> 8], 1);
    }
    __syncthreads();
    partS[chunk * 256 + tid] = hS[tid];
    partD[chunk * 256 + tid] = hD[tid];
}

__global__ __launch_bounds__(256) void scan_chunks(int* partS, int* partD,
                                                   int* totS, int* totD, int nchunk) {
    __shared__ int sums[256];
    int tid = threadIdx.x;
    int bin = blockIdx.x & 255;
    int* part = (blockIdx.x >> 8) ? partD : partS;
    int* tot  = (blockIdx.x >> 8) ? totD : totS;
    int v[4];
    int base = tid * 4, local = 0;
#pragma unroll
    for (int j = 0; j < 4; j++) {
        int c = base + j;
        v[j] = (c < nchunk) ? part[c * 256 + bin] : 0;
        local += v[j];
    }
    sums[tid] = local;
    __syncthreads();
    for (int off = 1; off < 256; off <<= 1) {
        int t = (tid >= off) ? sums[tid - off] : 0;
        __syncthreads();
        sums[tid] += t;
        __syncthreads();
    }
    int run = sums[tid] - local;
#pragma unroll
    for (int j = 0; j < 4; j++) {
        int c = base + j;
        if (c < nchunk) part[c * 256 + bin] = run;
        run += v[j];
    }
    if (tid == 255) tot[bin] = run;
}

__global__ __launch_bounds__(256) void scan_bins(const int* __restrict__ totS,
                                                 const int* __restrict__ totD,
                                                 int* baseS, int* baseD) {
    __shared__ int s[256];
    int tid = threadIdx.x;
    int v = totS[tid];
    s[tid] = v;
    __syncthreads();
    for (int off = 1; off < 256; off <<= 1) {
        int t = (tid >= off) ? s[tid - off] : 0;
        __syncthreads();
        s[tid] += t;
        __syncthreads();
    }
    baseS[tid] = s[tid] - v;
    __syncthreads();
    v = totD[tid];
    s[tid] = v;
    __syncthreads();
    for (int off = 1; off < 256; off <<= 1) {
        int t = (tid >= off) ? s[tid - off] : 0;
        __syncthreads();
        s[tid] += t;
        __syncthreads();
    }
    baseD[tid] = s[tid] - v;
}

__global__ __launch_bounds__(256) void partition_coarse(const int* __restrict__ src,
                                                        const int* __restrict__ dst,
                                                        const int* __restrict__ partS,
                                                        const int* __restrict__ partD,
                                                        const int* __restrict__ baseS,
                                                        const int* __restrict__ baseD,
                                                        unsigned int* __restrict__ packD,
                                                        unsigned char* __restrict__ srcLow,
                                                        int E, int chunkE) {
    __shared__ int curS[256], curD[256];
    int tid = threadIdx.x, chunk = blockIdx.x;
    curS[tid] = baseS[tid] + partS[chunk * 256 + tid];
    curD[tid] = baseD[tid] + partD[chunk * 256 + tid];
    __syncthreads();
    int e0 = chunk * chunkE, e1 = min(E, e0 + chunkE);
    for (int e = e0 + tid; e < e1; e += 256) {
        int s = src[e], d = dst[e];
        int pD = atomicAdd(&curD[d >> 8], 1);
        packD[pD] = ((unsigned)(d & 255) << 16) | (unsigned)s;
        int pS = atomicAdd(&curS[s >> 8], 1);
        srcLow[pS] = (unsigned char)(s & 255);
    }
}

__global__ __launch_bounds__(256) void fine_dst(const unsigned int* __restrict__ packD,
                                                const int* __restrict__ baseD,
                                                const int* __restrict__ totD,
                                                int* __restrict__ sorted_src,
                                                int* __restrict__ offs, int* __restrict__ cnt,
                                                float* __restrict__ norm_dst, int N) {
    __shared__ int hist[256], pfx[256], cur[256];
    int tid = threadIdx.x, b = blockIdx.x;
    int lo = baseD[b], n = totD[b];
    hist[tid] = 0;
    __syncthreads();
    for (int i = lo + tid; i < lo + n; i += 256) atomicAdd(&hist[packD[i] >> 16], 1);
    __syncthreads();
    int v = hist[tid];
    pfx[tid] = v;
    __syncthreads();
    for (int off = 1; off < 256; off <<= 1) {
        int t = (tid >= off) ? pfx[tid - off] : 0;
        __syncthreads();
        pfx[tid] += t;
        __syncthreads();
    }
    int my = pfx[tid] - v;
    cur[tid] = lo + my;
    int node = b * 256 + tid;
    if (node < N) {
        offs[node] = lo + my;
        cnt[node] = v;
        norm_dst[node] = rsqrtf(fmaxf((float)v, 1.0f));
    }
    __syncthreads();
    for (int i = lo + tid; i < lo + n; i += 256) {
        unsigned p = packD[i];
        int pos = atomicAdd(&cur[p >> 16], 1);
        sorted_src[pos] = (int)(p & 0xFFFFu);
    }
}

__global__ __launch_bounds__(256) void fine_src(const unsigned char* __restrict__ srcLow,
                                                const int* __restrict__ baseS,
                                                const int* __restrict__ totS,
                                                float* __restrict__ norm_src, int N) {
    __shared__ int hist[256];
    int tid = threadIdx.x, b = blockIdx.x;
    int lo = baseS[b], n = totS[b];
    hist[tid] = 0;
    __syncthreads();
    for (int i = lo + tid; i < lo + n; i += 256) atomicAdd(&hist[srcLow[i]], 1);
    __syncthreads();
    int node = b * 256 + tid;
    if (node < N) norm_src[node] = rsqrtf(fmaxf((float)hist[tid], 1.0f));
}

// ---------------- MFMA GEMM layer 1 (R6/R8 proven) ----------------

__global__ __launch_bounds__(256) void gemm1_kernel(const float* __restrict__ X,
                                                    const float* __restrict__ W1,
                                                    const float* __restrict__ norm_src,
                                                    __half* __restrict__ h1, int N) {
    __shared__ _Float16 sWt[64 * 72];
    __shared__ float snorm[128];
    __shared__ _Float16 sTile[4][16 * 72];
    int tid = threadIdx.x;
    int row_blk = blockIdx.x * 128;
    for (int i = tid; i < 4096; i += 256) {
        int k = i >> 6, n = i & 63;
        sWt[n * 72 + k] = (_Float16)W1[i];
    }
    if (tid < 128) {
        int r = row_blk + tid;
        snorm[tid] = (r < N) ? norm_src[r] : 0.f;
    }
    __syncthreads();
    int wave = tid >> 6, lane = tid & 63;
    int m = lane & 15, quad = lane >> 4;
    f16x8 bfrag[4][2];
#pragma unroll
    for (int nt = 0; nt < 4; nt++)
#pragma unroll
        for (int kit = 0; kit < 2; kit++)
            bfrag[nt][kit] = *(const f16x8*)&sWt[(nt * 16 + m) * 72 + kit * 32 + quad * 8];
    _Float16* tile = sTile[wave];
#pragma unroll
    for (int t = 0; t < 2; t++) {
        int row0 = row_blk + wave * 32 + t * 16;
        int row = row0 + m;
        bool inb = row < N;
        f32x4 acc[4] = {{0.f,0.f,0.f,0.f},{0.f,0.f,0.f,0.f},{0.f,0.f,0.f,0.f},{0.f,0.f,0.f,0.f}};
#pragma unroll
        for (int kit = 0; kit < 2; kit++) {
            f16x8 afrag;
            if (inb) {
                const float4* xp = (const float4*)(X + (size_t)row * 64 + kit * 32 + quad * 8);
                float4 x0 = xp[0], x1 = xp[1];
                afrag[0] = (_Float16)x0.x; afrag[1] = (_Float16)x0.y;
                afrag[2] = (_Float16)x0.z; afrag[3] = (_Float16)x0.w;
                afrag[4] = (_Float16)x1.x; afrag[5] = (_Float16)x1.y;
                afrag[6] = (_Float16)x1.z; afrag[7] = (_Float16)x1.w;
            } else {
#pragma unroll
                for (int j = 0; j < 8; j++) afrag[j] = (_Float16)0.f;
            }
#pragma unroll
            for (int nt = 0; nt < 4; nt++)
                acc[nt] = __builtin_amdgcn_mfma_f32_16x16x32_f16(afrag, bfrag[nt][kit], acc[nt], 0, 0, 0);
        }
#pragma unroll
        for (int reg = 0; reg < 4; reg++) {
            int r = quad * 4 + reg;
            float nrm = snorm[wave * 32 + t * 16 + r];
#pragma unroll
            for (int nt = 0; nt < 4; nt++)
                tile[r * 72 + nt * 16 + m] = (_Float16)(acc[nt][reg] * nrm);
        }
        __syncthreads();
        int rr = lane >> 2, g = lane & 3;
        f16x8 p0 = *(const f16x8*)&tile[rr * 72 + g * 16];
        f16x8 p1 = *(const f16x8*)&tile[rr * 72 + g * 16 + 8];
        int orow = row0 + rr;
        if (orow < N) {
            *(f16x8*)((_Float16*)h1 + (size_t)orow * 64 + g * 16) = p0;
            *(f16x8*)((_Float16*)h1 + (size_t)orow * 64 + g * 16 + 8) = p1;
        }
        __syncthreads();
    }
}

// ---------------- fused agg1 + relu + W2 matvec -> h2 (R9-proven logic) ----------------

__global__ __launch_bounds__(256) void agg1_fused(const __half* __restrict__ h1,
                                                  const int* __restrict__ sorted_src,
                                                  const int* __restrict__ offs,
                                                  const int* __restrict__ cnt,
                                                  const float* __restrict__ norm_dst,
                                                  const float* __restrict__ norm_src,
                                                  const float* __restrict__ b1,
                                                  const float* __restrict__ W2,
                                                  __half* __restrict__ h2, int N, int nwaves) {
    int tid = threadIdx.x;
    int wave = tid >> 6, lane = tid & 63;
    int e_off = lane >> 3;   // 0..7
    int fg = lane & 7;       // feats 8fg..8fg+7
    float w2r[8][2], b1r[8];
#pragma unroll
    for (int k = 0; k < 8; k++) {
        float2 t = *(const float2*)(W2 + (size_t)(fg * 8 + k) * 16 + 2 * e_off);
        w2r[k][0] = t.x; w2r[k][1] = t.y;
        b1r[k] = b1[fg * 8 + k];
    }
    const _Float16* h1p = (const _Float16*)h1;
    for (int row = blockIdx.x * 4 + wave; row < N; row += nwaves) {
        int start = offs[row], c = cnt[row];
        float nd = norm_dst[row];
        float acc[8] = {0.f, 0.f, 0.f, 0.f, 0.f, 0.f, 0.f, 0.f};
        for (int j = 0; j < c; j += 8) {
            int je = j + e_off;
            if (je < c) {
                int s = sorted_src[start + je];
                f16x8 v = *(const f16x8*)(h1p + (size_t)s * 64 + fg * 8);
#pragma unroll
                for (int k = 0; k < 8; k++) acc[k] += (float)v[k];
            }
        }
#pragma unroll
        for (int m = 8; m <= 32; m <<= 1)
#pragma unroll
            for (int k = 0; k < 8; k++) acc[k] += __shfl_xor(acc[k], m);
        float p0 = 0.f, p1 = 0.f;
#pragma unroll
        for (int k = 0; k < 8; k++) {
            float t = fmaxf(acc[k] * nd + b1r[k], 0.f);
            p0 += t * w2r[k][0];
            p1 += t * w2r[k][1];
        }
#pragma unroll
        for (int m = 1; m <= 4; m <<= 1) {
            p0 += __shfl_xor(p0, m);
            p1 += __shfl_xor(p1, m);
        }
        if (fg == 0) {
            float ns = norm_src[row];
            ((__half2*)((_Float16*)h2 + (size_t)row * 16))[e_off] =
                __floats2half2_rn(p0 * ns, p1 * ns);
        }
    }
}

// ---------------- layer-2 aggregation + epilogue: 16-B gathers ----------------
// lane = e_off(0..31) x fg(0..1); fg selects 16-B half of the 32-B h2 row.
// 2 loads/edge, 32 edges in flight per iteration.
__global__ __launch_bounds__(256) void agg2_kernel(const __half* __restrict__ h2,
                                                   const int* __restrict__ sorted_src,
                                                   const int* __restrict__ offs,
                                                   const int* __restrict__ cnt,
                                                   const float* __restrict__ norm_dst,
                                                   const float* __restrict__ b2,
                                                   float* __restrict__ out, int N) {
    int tid = threadIdx.x;
    int row = blockIdx.x * 4 + (tid >> 6);
    if (row >= N) return;
    int lane = tid & 63;
    int fg = lane & 1;       // feats 8fg..8fg+7
    int e_off = lane >> 1;   // 0..31
    int start = offs[row], c = cnt[row];
    float acc[8] = {0.f, 0.f, 0.f, 0.f, 0.f, 0.f, 0.f, 0.f};
    const _Float16* h2p = (const _Float16*)h2;
    for (int j = 0; j < c; j += 32) {
        int je = j + e_off;
        if (je < c) {
            int s = sorted_src[start + je];
            f16x8 v = *(const f16x8*)(h2p + (size_t)s * 16 + fg * 8);
#pragma unroll
            for (int k = 0; k < 8; k++) acc[k] += (float)v[k];
        }
    }
#pragma unroll
    for (int m = 2; m <= 32; m <<= 1)
#pragma unroll
        for (int k = 0; k < 8; k++) acc[k] += __shfl_xor(acc[k], m);
    if (e_off == 0) {
        float nd = norm_dst[row];
        float o[8];
#pragma unroll
        for (int k = 0; k < 8; k++) o[k] = acc[k] * nd + b2[fg * 8 + k];
        float* op = out + (size_t)row * 16 + fg * 8;
        *(float4*)op = make_float4(o[0], o[1], o[2], o[3]);
        *(float4*)(op + 4) = make_float4(o[4], o[5], o[6], o[7]);
    }
}

extern "C" void kernel_launch(void* const* d_in, const int* in_sizes, int n_in,
                              void* d_out, int out_size, void* d_ws, size_t ws_size,
                              hipStream_t stream) {
    const float* X  = (const float*)d_in[0];
    const int* src  = (const int*)d_in[1];
    const int* dst  = (const int*)d_in[2];
    const float* W1 = (const float*)d_in[3];
    const float* b1 = (const float*)d_in[4];
    const float* W2 = (const float*)d_in[5];
    const float* b2 = (const float*)d_in[6];
    float* out = (float*)d_out;

    const int N = in_sizes[0] / FEAT1;  // 50000
    const int E = in_sizes[1];          // 800000
    const int chunkE = (E + NCHUNK_R - 1) / NCHUNK_R;  // 1000

    char* w = (char*)d_ws;
    int* partS = (int*)w;        w += (size_t)NCHUNK_R * 256 * 4;
    int* partD = (int*)w;        w += (size_t)NCHUNK_R * 256 * 4;
    int* totS  = (int*)w;        w += 256 * 4;
    int* totD  = (int*)w;        w += 256 * 4;
    int* baseS = (int*)w;        w += 256 * 4;
    int* baseD = (int*)w;        w += 256 * 4;
    unsigned int* packD = (unsigned int*)w; w += (size_t)E * 4;
    int* sorted_src = (int*)w;   w += (size_t)E * 4;
    int* offs = (int*)w;         w += (size_t)N * 4;
    int* cnt  = (int*)w;         w += (size_t)N * 4;
    float* norm_src = (float*)w; w += (size_t)N * 4;
    float* norm_dst = (float*)w; w += (size_t)N * 4;
    __half* h1 = (__half*)w;     w += (size_t)N * 64 * 2;
    __half* h2 = (__half*)w;     w += (size_t)N * 16 * 2;
    unsigned char* srcLow = (unsigned char*)w; w += (size_t)E;

    coarse_hist<<<NCHUNK_R, 256, 0, stream>>>(src, dst, partS, partD, E, chunkE);
    scan_chunks<<<512, 256, 0, stream>>>(partS, partD, totS, totD, NCHUNK_R);
    scan_bins<<<1, 256, 0, stream>>>(totS, totD, baseS, baseD);
    partition_coarse<<<NCHUNK_R, 256, 0, stream>>>(src, dst, partS, partD, baseS, baseD,
                                                   packD, srcLow, E, chunkE);
    fine_dst<<<256, 256, 0, stream>>>(packD, baseD, totD, sorted_src, offs, cnt, norm_dst, N);
    fine_src<<<256, 256, 0, stream>>>(srcLow, baseS, totS, norm_src, N);
    gemm1_kernel<<<(N + 127) / 128, 256, 0, stream>>>(X, W1, norm_src, h1, N);
    const int nblk = 2048;
    agg1_fused<<<nblk, 256, 0, stream>>>(h1, sorted_src, offs, cnt, norm_dst, norm_src,
                                         b1, W2, h2, N, nblk * 4);
    agg2_kernel<<<(N + 3) / 4, 256, 0, stream>>>(h2, sorted_src, offs, cnt, norm_dst, b2, out, N);
}

// Round 11
// 176.418 us; speedup vs baseline: 1.0792x; 1.0283x over previous
//
#include <hip/hip_runtime.h>
#include <hip/hip_fp16.h>

#define FEAT1 64
#define FEAT2 16
#define NCHUNK_R 800   // radix chunks

typedef _Float16 f16x8 __attribute__((ext_vector_type(8)));
typedef _Float16 f16x4 __attribute__((ext_vector_type(4)));
typedef float f32x4 __attribute__((ext_vector_type(4)));

// ---------------- radix sort pipeline (R8-proven 256-bucket geometry) ----------------

__global__ __launch_bounds__(256) void coarse_hist(const int* __restrict__ src,
                                                   const int* __restrict__ dst,
                                                   int* __restrict__ partS, int* __restrict__ partD,
                                                   int E, int chunkE) {
    __shared__ int hS[256], hD[256];
    int tid = threadIdx.x, chunk = blockIdx.x;
    hS[tid] = 0; hD[tid] = 0;
    __syncthreads();
    int e0 = chunk * chunkE, e1 = min(E, e0 + chunkE);
    for (int e = e0 + tid; e < e1; e += 256) {
        atomicAdd(&hS[src[e] >> 8], 1);
        atomicAdd(&hD[dst[e] >> 8], 1);
    }
    __syncthreads();
    partS[chunk * 256 + tid] = hS[tid];
    partD[chunk * 256 + tid] = hD[tid];
}

__global__ __launch_bounds__(256) void scan_chunks(int* partS, int* partD,
                                                   int* totS, int* totD, int nchunk) {
    __shared__ int sums[256];
    int tid = threadIdx.x;
    int bin = blockIdx.x & 255;
    int* part = (blockIdx.x >> 8) ? partD : partS;
    int* tot  = (blockIdx.x >> 8) ? totD : totS;
    int v[4];
    int base = tid * 4, local = 0;
#pragma unroll
    for (int j = 0; j < 4; j++) {
        int c = base + j;
        v[j] = (c < nchunk) ? part[c * 256 + bin] : 0;
        local += v[j];
    }
    sums[tid] = local;
    __syncthreads();
    for (int off = 1; off < 256; off <<= 1) {
        int t = (tid >= off) ? sums[tid - off] : 0;
        __syncthreads();
        sums[tid] += t;
        __syncthreads();
    }
    int run = sums[tid] - local;
#pragma unroll
    for (int j = 0; j < 4; j++) {
        int c = base + j;
        if (c < nchunk) part[c * 256 + bin] = run;
        run += v[j];
    }
    if (tid == 255) tot[bin] = run;
}

__global__ __launch_bounds__(256) void scan_bins(const int* __restrict__ totS,
                                                 const int* __restrict__ totD,
                                                 int* baseS, int* baseD) {
    __shared__ int s[256];
    int tid = threadIdx.x;
    int v = totS[tid];
    s[tid] = v;
    __syncthreads();
    for (int off = 1; off < 256; off <<= 1) {
        int t = (tid >= off) ? s[tid - off] : 0;
        __syncthreads();
        s[tid] += t;
        __syncthreads();
    }
    baseS[tid] = s[tid] - v;
    __syncthreads();
    v = totD[tid];
    s[tid] = v;
    __syncthreads();
    for (int off = 1; off < 256; off <<= 1) {
        int t = (tid >= off) ? s[tid - off] : 0;
        __syncthreads();
        s[tid] += t;
        __syncthreads();
    }
    baseD[tid] = s[tid] - v;
}

__global__ __launch_bounds__(256) void partition_coarse(const int* __restrict__ src,
                                                        const int* __restrict__ dst,
                                                        const int* __restrict__ partS,
                                                        const int* __restrict__ partD,
                                                        const int* __restrict__ baseS,
                                                        const int* __restrict__ baseD,
                                                        unsigned int* __restrict__ packD,
                                                        unsigned char* __restrict__ srcLow,
                                                        int E, int chunkE) {
    __shared__ int curS[256], curD[256];
    int tid = threadIdx.x, chunk = blockIdx.x;
    curS[tid] = baseS[tid] + partS[chunk * 256 + tid];
    curD[tid] = baseD[tid] + partD[chunk * 256 + tid];
    __syncthreads();
    int e0 = chunk * chunkE, e1 = min(E, e0 + chunkE);
    for (int e = e0 + tid; e < e1; e += 256) {
        int s = src[e], d = dst[e];
        int pD = atomicAdd(&curD[d >> 8], 1);
        packD[pD] = ((unsigned)(d & 255) << 16) | (unsigned)s;
        int pS = atomicAdd(&curS[s >> 8], 1);
        srcLow[pS] = (unsigned char)(s & 255);
    }
}

// merged fine stage: blocks 0..255 = dst buckets (sort + offs/cnt/norm_dst),
// blocks 256..511 = src buckets (histogram -> norm_src)
__global__ __launch_bounds__(256) void fine_both(const unsigned int* __restrict__ packD,
                                                 const int* __restrict__ baseD,
                                                 const int* __restrict__ totD,
                                                 int* __restrict__ sorted_src,
                                                 int* __restrict__ offs, int* __restrict__ cnt,
                                                 float* __restrict__ norm_dst,
                                                 const unsigned char* __restrict__ srcLow,
                                                 const int* __restrict__ baseS,
                                                 const int* __restrict__ totS,
                                                 float* __restrict__ norm_src, int N) {
    __shared__ int hist[256], pfx[256], cur[256];
    int tid = threadIdx.x;
    if (blockIdx.x < 256) {
        int b = blockIdx.x;
        int lo = baseD[b], n = totD[b];
        hist[tid] = 0;
        __syncthreads();
        for (int i = lo + tid; i < lo + n; i += 256) atomicAdd(&hist[packD[i] >> 16], 1);
        __syncthreads();
        int v = hist[tid];
        pfx[tid] = v;
        __syncthreads();
        for (int off = 1; off < 256; off <<= 1) {
            int t = (tid >= off) ? pfx[tid - off] : 0;
            __syncthreads();
            pfx[tid] += t;
            __syncthreads();
        }
        int my = pfx[tid] - v;
        cur[tid] = lo + my;
        int node = b * 256 + tid;
        if (node < N) {
            offs[node] = lo + my;
            cnt[node] = v;
            norm_dst[node] = rsqrtf(fmaxf((float)v, 1.0f));
        }
        __syncthreads();
        for (int i = lo + tid; i < lo + n; i += 256) {
            unsigned p = packD[i];
            int pos = atomicAdd(&cur[p >> 16], 1);
            sorted_src[pos] = (int)(p & 0xFFFFu);
        }
    } else {
        int b = blockIdx.x - 256;
        int lo = baseS[b], n = totS[b];
        hist[tid] = 0;
        __syncthreads();
        for (int i = lo + tid; i < lo + n; i += 256) atomicAdd(&hist[srcLow[i]], 1);
        __syncthreads();
        int node = b * 256 + tid;
        if (node < N) norm_src[node] = rsqrtf(fmaxf((float)hist[tid], 1.0f));
    }
}

// ---------------- MFMA GEMM layer 1 (R6/R8 proven) ----------------

__global__ __launch_bounds__(256) void gemm1_kernel(const float* __restrict__ X,
                                                    const float* __restrict__ W1,
                                                    const float* __restrict__ norm_src,
                                                    __half* __restrict__ h1, int N) {
    __shared__ _Float16 sWt[64 * 72];
    __shared__ float snorm[128];
    __shared__ _Float16 sTile[4][16 * 72];
    int tid = threadIdx.x;
    int row_blk = blockIdx.x * 128;
    for (int i = tid; i < 4096; i += 256) {
        int k = i >> 6, n = i & 63;
        sWt[n * 72 + k] = (_Float16)W1[i];
    }
    if (tid < 128) {
        int r = row_blk + tid;
        snorm[tid] = (r < N) ? norm_src[r] : 0.f;
    }
    __syncthreads();
    int wave = tid >> 6, lane = tid & 63;
    int m = lane & 15, quad = lane >> 4;
    f16x8 bfrag[4][2];
#pragma unroll
    for (int nt = 0; nt < 4; nt++)
#pragma unroll
        for (int kit = 0; kit < 2; kit++)
            bfrag[nt][kit] = *(const f16x8*)&sWt[(nt * 16 + m) * 72 + kit * 32 + quad * 8];
    _Float16* tile = sTile[wave];
#pragma unroll
    for (int t = 0; t < 2; t++) {
        int row0 = row_blk + wave * 32 + t * 16;
        int row = row0 + m;
        bool inb = row < N;
        f32x4 acc[4] = {{0.f,0.f,0.f,0.f},{0.f,0.f,0.f,0.f},{0.f,0.f,0.f,0.f},{0.f,0.f,0.f,0.f}};
#pragma unroll
        for (int kit = 0; kit < 2; kit++) {
            f16x8 afrag;
            if (inb) {
                const float4* xp = (const float4*)(X + (size_t)row * 64 + kit * 32 + quad * 8);
                float4 x0 = xp[0], x1 = xp[1];
                afrag[0] = (_Float16)x0.x; afrag[1] = (_Float16)x0.y;
                afrag[2] = (_Float16)x0.z; afrag[3] = (_Float16)x0.w;
                afrag[4] = (_Float16)x1.x; afrag[5] = (_Float16)x1.y;
                afrag[6] = (_Float16)x1.z; afrag[7] = (_Float16)x1.w;
            } else {
#pragma unroll
                for (int j = 0; j < 8; j++) afrag[j] = (_Float16)0.f;
            }
#pragma unroll
            for (int nt = 0; nt < 4; nt++)
                acc[nt] = __builtin_amdgcn_mfma_f32_16x16x32_f16(afrag, bfrag[nt][kit], acc[nt], 0, 0, 0);
        }
#pragma unroll
        for (int reg = 0; reg < 4; reg++) {
            int r = quad * 4 + reg;
            float nrm = snorm[wave * 32 + t * 16 + r];
#pragma unroll
            for (int nt = 0; nt < 4; nt++)
                tile[r * 72 + nt * 16 + m] = (_Float16)(acc[nt][reg] * nrm);
        }
        __syncthreads();
        int rr = lane >> 2, g = lane & 3;
        f16x8 p0 = *(const f16x8*)&tile[rr * 72 + g * 16];
        f16x8 p1 = *(const f16x8*)&tile[rr * 72 + g * 16 + 8];
        int orow = row0 + rr;
        if (orow < N) {
            *(f16x8*)((_Float16*)h1 + (size_t)orow * 64 + g * 16) = p0;
            *(f16x8*)((_Float16*)h1 + (size_t)orow * 64 + g * 16 + 8) = p1;
        }
        __syncthreads();
    }
}

// ---------------- fused agg1 + relu + W2 matvec -> h2 ----------------

__global__ __launch_bounds__(256) void agg1_fused(const __half* __restrict__ h1,
                                                  const int* __restrict__ sorted_src,
                                                  const int* __restrict__ offs,
                                                  const int* __restrict__ cnt,
                                                  const float* __restrict__ norm_dst,
                                                  const float* __restrict__ norm_src,
                                                  const float* __restrict__ b1,
                                                  const float* __restrict__ W2,
                                                  __half* __restrict__ h2, int N, int nwaves) {
    int tid = threadIdx.x;
    int wave = tid >> 6, lane = tid & 63;
    int e_off = lane >> 3;   // 0..7
    int fg = lane & 7;       // feats 8fg..8fg+7
    float w2r[8][2], b1r[8];
#pragma unroll
    for (int k = 0; k < 8; k++) {
        float2 t = *(const float2*)(W2 + (size_t)(fg * 8 + k) * 16 + 2 * e_off);
        w2r[k][0] = t.x; w2r[k][1] = t.y;
        b1r[k] = b1[fg * 8 + k];
    }
    const _Float16* h1p = (const _Float16*)h1;
    for (int row = blockIdx.x * 4 + wave; row < N; row += nwaves) {
        int start = offs[row], c = cnt[row];
        float nd = norm_dst[row];
        float acc[8] = {0.f, 0.f, 0.f, 0.f, 0.f, 0.f, 0.f, 0.f};
        for (int j = 0; j < c; j += 8) {
            int je = j + e_off;
            if (je < c) {
                int s = sorted_src[start + je];
                f16x8 v = *(const f16x8*)(h1p + (size_t)s * 64 + fg * 8);
#pragma unroll
                for (int k = 0; k < 8; k++) acc[k] += (float)v[k];
            }
        }
#pragma unroll
        for (int m = 8; m <= 32; m <<= 1)
#pragma unroll
            for (int k = 0; k < 8; k++) acc[k] += __shfl_xor(acc[k], m);
        float p0 = 0.f, p1 = 0.f;
#pragma unroll
        for (int k = 0; k < 8; k++) {
            float t = fmaxf(acc[k] * nd + b1r[k], 0.f);
            p0 += t * w2r[k][0];
            p1 += t * w2r[k][1];
        }
#pragma unroll
        for (int m = 1; m <= 4; m <<= 1) {
            p0 += __shfl_xor(p0, m);
            p1 += __shfl_xor(p1, m);
        }
        if (fg == 0) {
            float ns = norm_src[row];
            ((__half2*)((_Float16*)h2 + (size_t)row * 16))[e_off] =
                __floats2half2_rn(p0 * ns, p1 * ns);
        }
    }
}

// ---------------- layer-2 aggregation + epilogue (R8-proven 8B form) ----------------

__global__ __launch_bounds__(256) void agg2_kernel(const __half* __restrict__ h2,
                                                   const int* __restrict__ sorted_src,
                                                   const int* __restrict__ offs,
                                                   const int* __restrict__ cnt,
                                                   const float* __restrict__ norm_dst,
                                                   const float* __restrict__ b2,
                                                   float* __restrict__ out, int N) {
    int tid = threadIdx.x;
    int row = blockIdx.x * 4 + (tid >> 6);
    if (row >= N) return;
    int lane = tid & 63;
    int e_off = lane >> 2;   // 0..15
    int fg = lane & 3;       // feats 4fg..4fg+3
    int start = offs[row], c = cnt[row];
    float acc[4] = {0.f, 0.f, 0.f, 0.f};
    const _Float16* h2p = (const _Float16*)h2;
    for (int j = 0; j < c; j += 16) {
        int je = j + e_off;
        if (je < c) {
            int s = sorted_src[start + je];
            f16x4 v = *(const f16x4*)(h2p + (size_t)s * 16 + fg * 4);
#pragma unroll
            for (int k = 0; k < 4; k++) acc[k] += (float)v[k];
        }
    }
#pragma unroll
    for (int m = 4; m <= 32; m <<= 1)
#pragma unroll
        for (int k = 0; k < 4; k++) acc[k] += __shfl_xor(acc[k], m);
    if (e_off == 0) {
        float nd = norm_dst[row];
        float4 o;
        o.x = acc[0] * nd + b2[fg * 4 + 0];
        o.y = acc[1] * nd + b2[fg * 4 + 1];
        o.z = acc[2] * nd + b2[fg * 4 + 2];
        o.w = acc[3] * nd + b2[fg * 4 + 3];
        ((float4*)(out + (size_t)row * 16))[fg] = o;
    }
}

extern "C" void kernel_launch(void* const* d_in, const int* in_sizes, int n_in,
                              void* d_out, int out_size, void* d_ws, size_t ws_size,
                              hipStream_t stream) {
    const float* X  = (const float*)d_in[0];
    const int* src  = (const int*)d_in[1];
    const int* dst  = (const int*)d_in[2];
    const float* W1 = (const float*)d_in[3];
    const float* b1 = (const float*)d_in[4];
    const float* W2 = (const float*)d_in[5];
    const float* b2 = (const float*)d_in[6];
    float* out = (float*)d_out;

    const int N = in_sizes[0] / FEAT1;  // 50000
    const int E = in_sizes[1];          // 800000
    const int chunkE = (E + NCHUNK_R - 1) / NCHUNK_R;  // 1000

    char* w = (char*)d_ws;
    int* partS = (int*)w;        w += (size_t)NCHUNK_R * 256 * 4;
    int* partD = (int*)w;        w += (size_t)NCHUNK_R * 256 * 4;
    int* totS  = (int*)w;        w += 256 * 4;
    int* totD  = (int*)w;        w += 256 * 4;
    int* baseS = (int*)w;        w += 256 * 4;
    int* baseD = (int*)w;        w += 256 * 4;
    unsigned int* packD = (unsigned int*)w; w += (size_t)E * 4;
    int* sorted_src = (int*)w;   w += (size_t)E * 4;
    int* offs = (int*)w;         w += (size_t)N * 4;
    int* cnt  = (int*)w;         w += (size_t)N * 4;
    float* norm_src = (float*)w; w += (size_t)N * 4;
    float* norm_dst = (float*)w; w += (size_t)N * 4;
    __half* h1 = (__half*)w;     w += (size_t)N * 64 * 2;
    __half* h2 = (__half*)w;     w += (size_t)N * 16 * 2;
    unsigned char* srcLow = (unsigned char*)w; w += (size_t)E;

    coarse_hist<<<NCHUNK_R, 256, 0, stream>>>(src, dst, partS, partD, E, chunkE);
    scan_chunks<<<512, 256, 0, stream>>>(partS, partD, totS, totD, NCHUNK_R);
    scan_bins<<<1, 256, 0, stream>>>(totS, totD, baseS, baseD);
    partition_coarse<<<NCHUNK_R, 256, 0, stream>>>(src, dst, partS, partD, baseS, baseD,
                                                   packD, srcLow, E, chunkE);
    fine_both<<<512, 256, 0, stream>>>(packD, baseD, totD, sorted_src, offs, cnt, norm_dst,
                                       srcLow, baseS, totS, norm_src, N);
    gemm1_kernel<<<(N + 127) / 128, 256, 0, stream>>>(X, W1, norm_src, h1, N);
    const int nblk = 3072;
    agg1_fused<<<nblk, 256, 0, stream>>>(h1, sorted_src, offs, cnt, norm_dst, norm_src,
                                         b1, W2, h2, N, nblk * 4);
    agg2_kernel<<<(N + 3) / 4, 256, 0, stream>>>(h2, sorted_src, offs, cnt, norm_dst, b2, out, N);
}